// Round 1
// baseline (438.152 us; speedup 1.0000x reference)
//
#include <hip/hip_runtime.h>
#include <cstdint>
#include <cstddef>

// Sizes (fixed by the problem)
#define NB 8
#define SEQ 2048
#define CH 1024
#define NH 16
#define HD 64
#define MROWS (NB*SEQ)   // 16384
#define HALFC 512

typedef __attribute__((ext_vector_type(4))) float f32x4;
typedef __attribute__((ext_vector_type(8))) short s16x8;

__device__ __forceinline__ ushort f2bf(float f) {
    union { float f; unsigned u; } v; v.f = f;
    unsigned r = (v.u + 0x7FFFu + ((v.u >> 16) & 1u)) >> 16;
    return (ushort)r;
}
__device__ __forceinline__ float bf2f(ushort u) {
    union { unsigned u; float f; } v; v.u = ((unsigned)u) << 16;
    return v.f;
}
__device__ __forceinline__ void gload16(const void* g, void* l) {
    __builtin_amdgcn_global_load_lds((const __attribute__((address_space(1))) unsigned*)g,
                                     (__attribute__((address_space(3))) unsigned*)l, 16, 0, 0);
}

// ---------------- f32 -> bf16 convert ----------------
__global__ void cvt_bf16_kernel(const float* __restrict__ src, ushort* __restrict__ dst, int n4) {
    int i = blockIdx.x * 256 + threadIdx.x;
    if (i >= n4) return;
    f32x4 v = ((const f32x4*)src)[i];
    ushort4 o;
    o.x = f2bf(v[0]); o.y = f2bf(v[1]); o.z = f2bf(v[2]); o.w = f2bf(v[3]);
    ((ushort4*)dst)[i] = o;
}

// ---------------- rope cos/sin table: [SEQ][HALFC] ----------------
__global__ void rope_table_kernel(float* __restrict__ cosT, float* __restrict__ sinT) {
    int idx = blockIdx.x * 256 + threadIdx.x;   // < SEQ*HALFC
    int n = idx >> 9;
    int i = idx & 511;
    float freq = powf(10000.f, -(float)i * (1.f / 512.f));
    float a = (float)n * freq;
    float s, c;
    sincosf(a, &s, &c);
    cosT[idx] = c; sinT[idx] = s;
}

// ---------------- fused QKV projection GEMM ----------------
// C[m, o] = sum_k x[m,k] * W[o,k]  (B^T layout, both k-contiguous)
// grid (8 col-tiles, 128 row-tiles, 3 proj), block 256 = 4 waves (2x2), tile 128x128, BK=64
__global__ __launch_bounds__(256, 2) void qkv_gemm_kernel(
    const ushort* __restrict__ xb, const ushort* __restrict__ wb,
    const float* __restrict__ bq, const float* __restrict__ bk, const float* __restrict__ bv,
    const float* __restrict__ cosT, const float* __restrict__ sinT,
    ushort* __restrict__ qr, ushort* __restrict__ kr, ushort* __restrict__ vo,
    float* __restrict__ ksum)
{
    __shared__ ushort As[128 * 64];
    __shared__ ushort Bs[128 * 64];
    const int z = blockIdx.z;
    const ushort* w = wb + (size_t)z * CH * CH;
    const float* bias = (z == 0) ? bq : (z == 1) ? bk : bv;
    ushort* dst = (z == 0) ? qr : (z == 1) ? kr : vo;
    const int row0 = blockIdx.y * 128;
    const int col0 = blockIdx.x * 128;
    const int tid = threadIdx.x;
    const int lane = tid & 63;
    const int wid = tid >> 6;
    const int wm = (wid >> 1) * 64;
    const int wn = (wid & 1) * 64;

    f32x4 acc[4][4] = {};

    for (int kt = 0; kt < CH; kt += 64) {
        __syncthreads();
        #pragma unroll
        for (int i = 0; i < 4; ++i) {
            int cl = i * 256 + tid;
            int r = cl >> 3, ci = cl & 7;
            int sci = ci ^ (r & 7);   // pre-swizzled source -> linear LDS (G4/m173)
            gload16(xb + (size_t)(row0 + r) * CH + kt + sci * 8, (void*)&As[cl * 8]);
            gload16(w  + (size_t)(col0 + r) * CH + kt + sci * 8, (void*)&Bs[cl * 8]);
        }
        asm volatile("s_waitcnt vmcnt(0)" ::: "memory");
        __syncthreads();
        #pragma unroll
        for (int ks = 0; ks < 2; ++ks) {
            s16x8 af[4], bfr[4];
            #pragma unroll
            for (int mi = 0; mi < 4; ++mi) {
                int r = wm + mi * 16 + (lane & 15);
                int ch = ((lane >> 4) + ks * 4) ^ (r & 7);
                af[mi] = *(const s16x8*)&As[r * 64 + ch * 8];
            }
            #pragma unroll
            for (int ni = 0; ni < 4; ++ni) {
                int r = wn + ni * 16 + (lane & 15);
                int ch = ((lane >> 4) + ks * 4) ^ (r & 7);
                bfr[ni] = *(const s16x8*)&Bs[r * 64 + ch * 8];
            }
            #pragma unroll
            for (int mi = 0; mi < 4; ++mi)
                #pragma unroll
                for (int ni = 0; ni < 4; ++ni)
                    acc[mi][ni] = __builtin_amdgcn_mfma_f32_16x16x32_bf16(af[mi], bfr[ni], acc[mi][ni], 0, 0, 0);
        }
    }

    // epilogue: bias -> (gelu + 0.21, ksum, rope) or plain v
    const int bidx = row0 >> 11;  // batch index
    #pragma unroll
    for (int ni = 0; ni < 4; ++ni) {
        const int cg = col0 + wn + ni * 16 + (lane & 15);
        const float bsv = bias[cg];
        float cs = 0.f;
        #pragma unroll
        for (int mi = 0; mi < 4; ++mi) {
            const int mbase = row0 + wm + mi * 16 + ((lane >> 4) << 2);
            #pragma unroll
            for (int r = 0; r < 4; ++r) {
                float t = acc[mi][ni][r] + bsv;
                float val;
                if (z == 2) {
                    val = t;
                } else {
                    val = 0.5f * t * (1.f + erff(t * 0.7071067811865475f)) + 0.21f;  // exact GELU + 0.21
                }
                if (z == 1) cs += val;   // pre-rope k column sum
                if (z != 2) {
                    // interleaved-pair rope; partner col = cg^1 lives in lane^1 (col = lane&15)
                    float p = __shfl_xor(val, 1);
                    int n = (mbase + r) & (SEQ - 1);
                    float cv = cosT[n * HALFC + (cg >> 1)];
                    float sv = sinT[n * HALFC + (cg >> 1)];
                    val = (cg & 1) ? (p * sv + val * cv) : (val * cv - p * sv);
                }
                dst[(size_t)(mbase + r) * CH + cg] = f2bf(val);
            }
        }
        if (z == 1) {
            cs += __shfl_xor(cs, 16);
            cs += __shfl_xor(cs, 32);
            if (lane < 16) atomicAdd(&ksum[bidx * CH + cg], cs);
        }
    }
}

// ---------------- z = 1/(q . mean_n(k) + 1e-6) via rotated kmean ----------------
// q.km == q_r.R_n(km) (rope is a pairwise rotation within each head slice)
__global__ void z_kernel(const ushort* __restrict__ qr, const float* __restrict__ ksum,
                         const float* __restrict__ cosT, const float* __restrict__ sinT,
                         float* __restrict__ zout)
{
    int idx = blockIdx.x * 256 + threadIdx.x;   // < MROWS*NH
    int h = idx & 15;
    int m = idx >> 4;
    int b = m >> 11;
    int n = m & (SEQ - 1);
    const ushort* qp = qr + (size_t)m * CH + h * HD;
    const float* kmp = ksum + b * CH + h * HD;
    const float* cp = cosT + (size_t)n * HALFC + h * 32;
    const float* sp = sinT + (size_t)n * HALFC + h * 32;
    float dot = 0.f;
    #pragma unroll
    for (int i = 0; i < 32; ++i) {
        float c = cp[i], s = sp[i];
        float km0 = kmp[2 * i], km1 = kmp[2 * i + 1];
        float q0 = bf2f(qp[2 * i]), q1 = bf2f(qp[2 * i + 1]);
        dot += q0 * (km0 * c - km1 * s) + q1 * (km0 * s + km1 * c);
    }
    dot *= (1.f / 2048.f);   // ksum -> mean
    zout[((size_t)(b * NH + h)) * SEQ + n] = 1.f / (dot + 1e-6f);
}

// ---------------- kv partials: kvp[blk][d][e] = sum_{n in chunk} k_r[n,d]*v[n,e] ----------------
// grid = NB*NH*8 chunks of 256 rows, block 256, per-thread 4x4 patch
__global__ __launch_bounds__(256, 2) void kv_partial_kernel(
    const ushort* __restrict__ kr, const ushort* __restrict__ vo, float* __restrict__ kvp)
{
    const int blk = blockIdx.x;
    const int chunk = blk & 7;
    const int bh = blk >> 3;
    const int b = bh >> 4, h = bh & 15;
    __shared__ float ks[64 * 68];
    __shared__ float vs[64 * 68];
    const int tid = threadIdx.x;
    const int d0 = (tid >> 4) * 4;
    const int e0 = (tid & 15) * 4;
    float acc[4][4] = {};
    const size_t base = ((size_t)b * SEQ + chunk * 256) * CH + h * HD;
    const int lrow = tid >> 2;           // 0..63
    const int lcol = (tid & 3) * 16;

    for (int it = 0; it < 4; ++it) {
        __syncthreads();
        const ushort* gk = kr + base + (size_t)(it * 64 + lrow) * CH + lcol;
        const ushort* gv = vo + base + (size_t)(it * 64 + lrow) * CH + lcol;
        s16x8 ka = *(const s16x8*)gk, kb2 = *(const s16x8*)(gk + 8);
        s16x8 va = *(const s16x8*)gv, vb2 = *(const s16x8*)(gv + 8);
        #pragma unroll
        for (int seg = 0; seg < 2; ++seg) {
            s16x8 kk = seg ? kb2 : ka;
            s16x8 vv = seg ? vb2 : va;
            #pragma unroll
            for (int q = 0; q < 2; ++q) {
                f32x4 tk, tv;
                #pragma unroll
                for (int e = 0; e < 4; ++e) {
                    tk[e] = bf2f((ushort)kk[q * 4 + e]);
                    tv[e] = bf2f((ushort)vv[q * 4 + e]);
                }
                *(f32x4*)&ks[lrow * 68 + lcol + seg * 8 + q * 4] = tk;
                *(f32x4*)&vs[lrow * 68 + lcol + seg * 8 + q * 4] = tv;
            }
        }
        __syncthreads();
        for (int n = 0; n < 64; ++n) {
            f32x4 kq = *(const f32x4*)&ks[n * 68 + d0];
            f32x4 vq = *(const f32x4*)&vs[n * 68 + e0];
            #pragma unroll
            for (int di = 0; di < 4; ++di)
                #pragma unroll
                for (int ej = 0; ej < 4; ++ej)
                    acc[di][ej] += kq[di] * vq[ej];
        }
    }
    float* op = kvp + (size_t)blk * 4096;
    #pragma unroll
    for (int di = 0; di < 4; ++di) {
        f32x4 t;
        t[0] = acc[di][0]; t[1] = acc[di][1]; t[2] = acc[di][2]; t[3] = acc[di][3];
        *(f32x4*)&op[(d0 + di) * 64 + e0] = t;
    }
}

// ---------------- kv reduce: kvT[bh][e][d] (bf16) = (1/2048) * sum_c kvp ----------------
__global__ void kv_reduce_kernel(const float* __restrict__ kvp, ushort* __restrict__ kvT) {
    int idx = blockIdx.x * 256 + threadIdx.x;   // < 128*4096
    int bh = idx >> 12;
    int de = idx & 4095;
    int e = de >> 6, d = de & 63;
    float s = 0.f;
    #pragma unroll
    for (int c = 0; c < 8; ++c)
        s += kvp[((size_t)bh * 8 + c) * 4096 + d * 64 + e];
    kvT[idx] = f2bf(s * (1.f / 2048.f));
}

// ---------------- PV: o[n, h*64+e] = z * sum_d q_r[n,h*64+d] * kvT[e,d] ----------------
// grid (16 row-tiles, 128 bh), block 256 = 4 waves stacked in n; K=64, single K-tile
__global__ __launch_bounds__(256, 2) void pv_kernel(
    const ushort* __restrict__ qr, const ushort* __restrict__ kvT,
    const float* __restrict__ zin, ushort* __restrict__ o)
{
    __shared__ ushort As[128 * 64];
    __shared__ ushort Bs[64 * 64];
    const int bh = blockIdx.y;
    const int b = bh >> 4, h = bh & 15;
    const int row0 = blockIdx.x * 128;
    const int tid = threadIdx.x;
    const int lane = tid & 63, wid = tid >> 6;
    const size_t grow = (size_t)b * SEQ + row0;

    #pragma unroll
    for (int i = 0; i < 4; ++i) {
        int cl = i * 256 + tid;
        int r = cl >> 3, ci = cl & 7;
        int sci = ci ^ (r & 7);
        gload16(qr + (grow + r) * CH + h * HD + sci * 8, (void*)&As[cl * 8]);
    }
    #pragma unroll
    for (int i = 0; i < 2; ++i) {
        int cl = i * 256 + tid;
        int r = cl >> 3, ci = cl & 7;
        int sci = ci ^ (r & 7);
        gload16(kvT + (size_t)bh * 4096 + r * 64 + sci * 8, (void*)&Bs[cl * 8]);
    }
    asm volatile("s_waitcnt vmcnt(0)" ::: "memory");
    __syncthreads();

    f32x4 acc[2][4] = {};
    #pragma unroll
    for (int ks = 0; ks < 2; ++ks) {
        s16x8 af[2], bfr[4];
        #pragma unroll
        for (int mi = 0; mi < 2; ++mi) {
            int r = wid * 32 + mi * 16 + (lane & 15);
            int ch = ((lane >> 4) + ks * 4) ^ (r & 7);
            af[mi] = *(const s16x8*)&As[r * 64 + ch * 8];
        }
        #pragma unroll
        for (int ni = 0; ni < 4; ++ni) {
            int e = ni * 16 + (lane & 15);
            int ch = ((lane >> 4) + ks * 4) ^ (e & 7);
            bfr[ni] = *(const s16x8*)&Bs[e * 64 + ch * 8];
        }
        #pragma unroll
        for (int mi = 0; mi < 2; ++mi)
            #pragma unroll
            for (int ni = 0; ni < 4; ++ni)
                acc[mi][ni] = __builtin_amdgcn_mfma_f32_16x16x32_bf16(af[mi], bfr[ni], acc[mi][ni], 0, 0, 0);
    }

    const float* zp = zin + (size_t)bh * SEQ + row0;
    #pragma unroll
    for (int mi = 0; mi < 2; ++mi) {
        int mb = wid * 32 + mi * 16 + ((lane >> 4) << 2);
        #pragma unroll
        for (int r = 0; r < 4; ++r) {
            float zv = zp[mb + r];
            #pragma unroll
            for (int ni = 0; ni < 4; ++ni) {
                int e = ni * 16 + (lane & 15);
                o[(grow + mb + r) * CH + h * HD + e] = f2bf(acc[mi][ni][r] * zv);
            }
        }
    }
}

// ---------------- residual + LayerNorm ----------------
__global__ __launch_bounds__(256) void ln_kernel(
    const ushort* __restrict__ o, const float* __restrict__ x,
    const float* __restrict__ gamma, const float* __restrict__ beta,
    float* __restrict__ out)
{
    const int row = blockIdx.x;
    const int tid = threadIdx.x;
    const size_t base = (size_t)row * CH + tid * 4;
    f32x4 xv = *(const f32x4*)(x + base);
    ushort4 ov = *(const ushort4*)(o + base);
    float v0 = bf2f(ov.x) + xv[0];
    float v1 = bf2f(ov.y) + xv[1];
    float v2 = bf2f(ov.z) + xv[2];
    float v3 = bf2f(ov.w) + xv[3];
    float s = v0 + v1 + v2 + v3;
    float q = v0 * v0 + v1 * v1 + v2 * v2 + v3 * v3;
    #pragma unroll
    for (int off = 1; off < 64; off <<= 1) {
        s += __shfl_xor(s, off);
        q += __shfl_xor(q, off);
    }
    __shared__ float red[8];
    int wv = tid >> 6;
    if ((tid & 63) == 0) { red[wv] = s; red[4 + wv] = q; }
    __syncthreads();
    s = red[0] + red[1] + red[2] + red[3];
    q = red[4] + red[5] + red[6] + red[7];
    float mean = s * (1.f / 1024.f);
    float var = q * (1.f / 1024.f) - mean * mean;
    float rstd = rsqrtf(var + 1e-12f);
    f32x4 gv = *(const f32x4*)(gamma + tid * 4);
    f32x4 bv = *(const f32x4*)(beta + tid * 4);
    f32x4 res;
    res[0] = (v0 - mean) * rstd * gv[0] + bv[0];
    res[1] = (v1 - mean) * rstd * gv[1] + bv[1];
    res[2] = (v2 - mean) * rstd * gv[2] + bv[2];
    res[3] = (v3 - mean) * rstd * gv[3] + bv[3];
    *(f32x4*)(out + base) = res;
}

extern "C" void kernel_launch(void* const* d_in, const int* in_sizes, int n_in,
                              void* d_out, int out_size, void* d_ws, size_t ws_size,
                              hipStream_t stream) {
    const float* x     = (const float*)d_in[0];
    const float* Wq    = (const float*)d_in[1];
    const float* bq    = (const float*)d_in[2];
    const float* Wk    = (const float*)d_in[3];
    const float* bk    = (const float*)d_in[4];
    const float* Wv    = (const float*)d_in[5];
    const float* bv    = (const float*)d_in[6];
    const float* gamma = (const float*)d_in[7];
    const float* beta  = (const float*)d_in[8];
    float* out = (float*)d_out;
    char* ws = (char*)d_ws;

    // workspace layout (bytes); total ~161 MiB
    ushort* xb   = (ushort*)(ws);                        // 32 MiB (reused as attn-out o)
    ushort* wb   = (ushort*)(ws + (size_t)38  * 0 + (size_t)32 * 1048576); // 6 MiB
    float*  cosT = (float*) (ws + (size_t)38  * 1048576); // 4 MiB
    float*  sinT = (float*) (ws + (size_t)42  * 1048576); // 4 MiB
    ushort* qr   = (ushort*)(ws + (size_t)46  * 1048576); // 32 MiB
    ushort* kr   = (ushort*)(ws + (size_t)78  * 1048576); // 32 MiB
    ushort* vo   = (ushort*)(ws + (size_t)110 * 1048576); // 32 MiB
    float*  ksum = (float*) (ws + (size_t)142 * 1048576); // 32 KiB
    ushort* kvT  = (ushort*)(ws + (size_t)143 * 1048576); // 1 MiB
    float*  zbuf = (float*) (ws + (size_t)144 * 1048576); // 1 MiB
    float*  kvp  = (float*) (ws + (size_t)145 * 1048576); // 16 MiB
    ushort* o    = xb;  // reuse: xb dead after qkv_gemm

    hipMemsetAsync(ksum, 0, NB * CH * sizeof(float), stream);
    cvt_bf16_kernel<<<16384, 256, 0, stream>>>(x, xb, MROWS * CH / 4);
    cvt_bf16_kernel<<<1024, 256, 0, stream>>>(Wq, wb,                 CH * CH / 4);
    cvt_bf16_kernel<<<1024, 256, 0, stream>>>(Wk, wb + CH * CH,       CH * CH / 4);
    cvt_bf16_kernel<<<1024, 256, 0, stream>>>(Wv, wb + 2 * CH * CH,   CH * CH / 4);
    rope_table_kernel<<<SEQ * HALFC / 256, 256, 0, stream>>>(cosT, sinT);
    qkv_gemm_kernel<<<dim3(8, 128, 3), 256, 0, stream>>>(xb, wb, bq, bk, bv, cosT, sinT, qr, kr, vo, ksum);
    z_kernel<<<MROWS * NH / 256, 256, 0, stream>>>(qr, ksum, cosT, sinT, zbuf);
    kv_partial_kernel<<<NB * NH * 8, 256, 0, stream>>>(kr, vo, kvp);
    kv_reduce_kernel<<<NB * NH * 4096 / 256, 256, 0, stream>>>(kvp, kvT);
    pv_kernel<<<dim3(16, 128), 256, 0, stream>>>(qr, kvT, zbuf, o);
    ln_kernel<<<MROWS, 256, 0, stream>>>(o, x, gamma, beta, out);
}

// Round 3
// 422.762 us; speedup vs baseline: 1.0364x; 1.0364x over previous
//
#include <hip/hip_runtime.h>
#include <cstdint>
#include <cstddef>

// Sizes (fixed by the problem)
#define NB 8
#define SEQ 2048
#define CH 1024
#define NH 16
#define HD 64
#define MROWS (NB*SEQ)   // 16384
#define HALFC 512

typedef __attribute__((ext_vector_type(4))) float f32x4;
typedef __attribute__((ext_vector_type(8))) short s16x8;

__device__ __forceinline__ ushort f2bf(float f) {
    union { float f; unsigned u; } v; v.f = f;
    unsigned r = (v.u + 0x7FFFu + ((v.u >> 16) & 1u)) >> 16;
    return (ushort)r;
}
__device__ __forceinline__ float bf2f(ushort u) {
    union { unsigned u; float f; } v; v.u = ((unsigned)u) << 16;
    return v.f;
}
__device__ __forceinline__ void gload16(const ushort* g, ushort* l) {
    __builtin_amdgcn_global_load_lds((const __attribute__((address_space(1))) unsigned*)g,
                                     (__attribute__((address_space(3))) unsigned*)l, 16, 0, 0);
}

// A&S 7.1.26 erf approximation, |err| <= 1.5e-7 (validated correct in round-2 eager pass)
__device__ __forceinline__ float fast_erf(float x) {
    float ax = fabsf(x);
    float d = __fmaf_rn(0.3275911f, ax, 1.f);
    float t; asm("v_rcp_f32 %0, %1" : "=v"(t) : "v"(d));
    float p = __fmaf_rn(1.061405429f, t, -1.453152027f);
    p = __fmaf_rn(p, t, 1.421413741f);
    p = __fmaf_rn(p, t, -0.284496736f);
    p = __fmaf_rn(p, t, 0.254829592f);
    p = p * t;
    float e = __expf(-ax * ax);
    float r = 1.f - p * e;
    return copysignf(r, x);
}

// ---------------- f32 -> bf16 convert ----------------
__global__ void cvt_bf16_kernel(const float* __restrict__ src, ushort* __restrict__ dst, int n4) {
    int i = blockIdx.x * 256 + threadIdx.x;
    if (i >= n4) return;
    f32x4 v = ((const f32x4*)src)[i];
    ushort4 o;
    o.x = f2bf(v[0]); o.y = f2bf(v[1]); o.z = f2bf(v[2]); o.w = f2bf(v[3]);
    ((ushort4*)dst)[i] = o;
}

// ---------------- rope cos/sin table (interleaved float2): [SEQ][HALFC] ----------------
__global__ void rope_table_kernel(float2* __restrict__ csT) {
    int idx = blockIdx.x * 256 + threadIdx.x;   // < SEQ*HALFC
    int n = idx >> 9;
    int i = idx & 511;
    float freq = powf(10000.f, -(float)i * (1.f / 512.f));
    float a = (float)n * freq;
    float s, c;
    sincosf(a, &s, &c);
    csT[idx] = make_float2(c, s);
}

// ---------------- fused QKV projection GEMM ----------------
// C[m, o] = sum_k x[m,k] * W[o,k]  (B^T layout, both k-contiguous)
// ROUND-1 PROVEN sync structure (sync; stage; vmcnt(0); sync; compute).
// NEW: T1 XCD-aware block swizzle for L2 panel reuse (pure index bijection).
// grid (8 col-tiles, 128 row-tiles, 3 proj), block 256 = 4 waves (2x2), tile 128x128, BK=64
__global__ __launch_bounds__(256, 2) void qkv_gemm_kernel(
    const ushort* __restrict__ xb, const ushort* __restrict__ wb,
    const float* __restrict__ bq, const float* __restrict__ bk, const float* __restrict__ bv,
    const float2* __restrict__ csT,
    ushort* __restrict__ qr, ushort* __restrict__ kr, ushort* __restrict__ vo,
    float* __restrict__ ksum)
{
    __shared__ ushort As[128 * 64];
    __shared__ ushort Bs[128 * 64];
    const int z = blockIdx.z;
    const ushort* w = wb + (size_t)z * CH * CH;
    const float* bias = (z == 0) ? bq : (z == 1) ? bk : bv;
    ushort* dst = (z == 0) ? qr : (z == 1) ? kr : vo;
    // XCD swizzle: physical block p -> XCD p%8; give XCD x the contiguous logical
    // range [x*128, (x+1)*128) (col-fastest) so its 8 B-panels (2 MiB) stay L2-resident
    // and A row-tiles are re-read 8x from L2 instead of HBM. 1024 blocks/z, 1024%8==0.
    const int bid = blockIdx.x + 8 * blockIdx.y;       // physical 0..1023
    const int l = (bid & 7) * 128 + (bid >> 3);        // logical, bijective
    const int row0 = (l >> 3) * 128;
    const int col0 = (l & 7) * 128;
    const int tid = threadIdx.x;
    const int lane = tid & 63;
    const int wid = tid >> 6;
    const int wm = (wid >> 1) * 64;
    const int wn = (wid & 1) * 64;

    f32x4 acc[4][4] = {};

    for (int kt = 0; kt < CH; kt += 64) {
        __syncthreads();
        #pragma unroll
        for (int i = 0; i < 4; ++i) {
            int cl = i * 256 + tid;
            int r = cl >> 3, ci = cl & 7;
            int sci = ci ^ (r & 7);   // pre-swizzled source -> linear LDS (G4/m173)
            gload16(xb + (size_t)(row0 + r) * CH + kt + sci * 8, (ushort*)&As[cl * 8]);
            gload16(w  + (size_t)(col0 + r) * CH + kt + sci * 8, (ushort*)&Bs[cl * 8]);
        }
        asm volatile("s_waitcnt vmcnt(0)" ::: "memory");
        __syncthreads();
        #pragma unroll
        for (int ks = 0; ks < 2; ++ks) {
            s16x8 af[4], bfr[4];
            #pragma unroll
            for (int mi = 0; mi < 4; ++mi) {
                int r = wm + mi * 16 + (lane & 15);
                int ch = ((lane >> 4) + ks * 4) ^ (r & 7);
                af[mi] = *(const s16x8*)&As[r * 64 + ch * 8];
            }
            #pragma unroll
            for (int ni = 0; ni < 4; ++ni) {
                int r = wn + ni * 16 + (lane & 15);
                int ch = ((lane >> 4) + ks * 4) ^ (r & 7);
                bfr[ni] = *(const s16x8*)&Bs[r * 64 + ch * 8];
            }
            #pragma unroll
            for (int mi = 0; mi < 4; ++mi)
                #pragma unroll
                for (int ni = 0; ni < 4; ++ni)
                    acc[mi][ni] = __builtin_amdgcn_mfma_f32_16x16x32_bf16(af[mi], bfr[ni], acc[mi][ni], 0, 0, 0);
        }
    }

    // epilogue: bias -> (fast-gelu + 0.21, ksum, rope) or plain v
    const int bidx = row0 >> 11;  // batch index
    #pragma unroll
    for (int ni = 0; ni < 4; ++ni) {
        const int cg = col0 + wn + ni * 16 + (lane & 15);
        const float bsv = bias[cg];
        float cs = 0.f;
        #pragma unroll
        for (int mi = 0; mi < 4; ++mi) {
            const int mbase = row0 + wm + mi * 16 + ((lane >> 4) << 2);
            #pragma unroll
            for (int r = 0; r < 4; ++r) {
                float t = acc[mi][ni][r] + bsv;
                float val;
                if (z == 2) {
                    val = t;
                } else {
                    val = 0.5f * t * (1.f + fast_erf(t * 0.70710678f)) + 0.21f;
                }
                if (z == 1) cs += val;   // pre-rope k column sum
                if (z != 2) {
                    // interleaved-pair rope; partner col = cg^1 lives in lane^1 (col = lane&15)
                    float p = __shfl_xor(val, 1);
                    int n = (mbase + r) & (SEQ - 1);
                    float2 cv = csT[n * HALFC + (cg >> 1)];
                    val = (cg & 1) ? (p * cv.y + val * cv.x) : (val * cv.x - p * cv.y);
                }
                dst[(size_t)(mbase + r) * CH + cg] = f2bf(val);
            }
        }
        if (z == 1) {
            cs += __shfl_xor(cs, 16);
            cs += __shfl_xor(cs, 32);
            if (lane < 16) atomicAdd(&ksum[bidx * CH + cg], cs);
        }
    }
}

// ---------------- z = 1/(q . mean_n(k) + 1e-6) via rotated kmean ----------------
// q.km == q_r.R_n(km) (rope is a pairwise rotation within each head slice)
__global__ void z_kernel(const ushort* __restrict__ qr, const float* __restrict__ ksum,
                         const float2* __restrict__ csT, float* __restrict__ zout)
{
    int idx = blockIdx.x * 256 + threadIdx.x;   // < MROWS*NH
    int h = idx & 15;
    int m = idx >> 4;
    int b = m >> 11;
    int n = m & (SEQ - 1);
    const ushort* qp = qr + (size_t)m * CH + h * HD;
    const float* kmp = ksum + b * CH + h * HD;
    const float2* cp = csT + (size_t)n * HALFC + h * 32;
    float dot = 0.f;
    #pragma unroll
    for (int i = 0; i < 32; ++i) {
        float2 cv = cp[i];
        float km0 = kmp[2 * i], km1 = kmp[2 * i + 1];
        float q0 = bf2f(qp[2 * i]), q1 = bf2f(qp[2 * i + 1]);
        dot += q0 * (km0 * cv.x - km1 * cv.y) + q1 * (km0 * cv.y + km1 * cv.x);
    }
    dot *= (1.f / 2048.f);   // ksum -> mean
    zout[((size_t)(b * NH + h)) * SEQ + n] = 1.f / (dot + 1e-6f);
}

// ---------------- kv partials: kvp[blk][d][e] = sum_{n in chunk} k_r[n,d]*v[n,e] ----------------
__global__ __launch_bounds__(256, 2) void kv_partial_kernel(
    const ushort* __restrict__ kr, const ushort* __restrict__ vo, float* __restrict__ kvp)
{
    const int blk = blockIdx.x;
    const int chunk = blk & 7;
    const int bh = blk >> 3;
    const int b = bh >> 4, h = bh & 15;
    __shared__ float ks[64 * 68];
    __shared__ float vs[64 * 68];
    const int tid = threadIdx.x;
    const int d0 = (tid >> 4) * 4;
    const int e0 = (tid & 15) * 4;
    float acc[4][4] = {};
    const size_t base = ((size_t)b * SEQ + chunk * 256) * CH + h * HD;
    const int lrow = tid >> 2;
    const int lcol = (tid & 3) * 16;

    for (int it = 0; it < 4; ++it) {
        __syncthreads();
        const ushort* gk = kr + base + (size_t)(it * 64 + lrow) * CH + lcol;
        const ushort* gv = vo + base + (size_t)(it * 64 + lrow) * CH + lcol;
        s16x8 ka = *(const s16x8*)gk, kb2 = *(const s16x8*)(gk + 8);
        s16x8 va = *(const s16x8*)gv, vb2 = *(const s16x8*)(gv + 8);
        #pragma unroll
        for (int seg = 0; seg < 2; ++seg) {
            s16x8 kk = seg ? kb2 : ka;
            s16x8 vv = seg ? vb2 : va;
            #pragma unroll
            for (int q = 0; q < 2; ++q) {
                f32x4 tk, tv;
                #pragma unroll
                for (int e = 0; e < 4; ++e) {
                    tk[e] = bf2f((ushort)kk[q * 4 + e]);
                    tv[e] = bf2f((ushort)vv[q * 4 + e]);
                }
                *(f32x4*)&ks[lrow * 68 + lcol + seg * 8 + q * 4] = tk;
                *(f32x4*)&vs[lrow * 68 + lcol + seg * 8 + q * 4] = tv;
            }
        }
        __syncthreads();
        for (int n = 0; n < 64; ++n) {
            f32x4 kq = *(const f32x4*)&ks[n * 68 + d0];
            f32x4 vq = *(const f32x4*)&vs[n * 68 + e0];
            #pragma unroll
            for (int di = 0; di < 4; ++di)
                #pragma unroll
                for (int ej = 0; ej < 4; ++ej)
                    acc[di][ej] += kq[di] * vq[ej];
        }
    }
    float* op = kvp + (size_t)blk * 4096;
    #pragma unroll
    for (int di = 0; di < 4; ++di) {
        f32x4 t;
        t[0] = acc[di][0]; t[1] = acc[di][1]; t[2] = acc[di][2]; t[3] = acc[di][3];
        *(f32x4*)&op[(d0 + di) * 64 + e0] = t;
    }
}

// ---------------- kv reduce: kvT[bh][e][d] (bf16) = (1/2048) * sum_c kvp ----------------
__global__ void kv_reduce_kernel(const float* __restrict__ kvp, ushort* __restrict__ kvT) {
    int idx = blockIdx.x * 256 + threadIdx.x;   // < 128*4096
    int bh = idx >> 12;
    int de = idx & 4095;
    int e = de >> 6, d = de & 63;
    float s = 0.f;
    #pragma unroll
    for (int c = 0; c < 8; ++c)
        s += kvp[((size_t)bh * 8 + c) * 4096 + d * 64 + e];
    kvT[idx] = f2bf(s * (1.f / 2048.f));
}

// ---------------- PV: o[n, h*64+e] = z * sum_d q_r[n,h*64+d] * kvT[e,d] ----------------
__global__ __launch_bounds__(256, 2) void pv_kernel(
    const ushort* __restrict__ qr, const ushort* __restrict__ kvT,
    const float* __restrict__ zin, ushort* __restrict__ o)
{
    __shared__ ushort As[128 * 64];
    __shared__ ushort Bs[64 * 64];
    const int bh = blockIdx.y;
    const int b = bh >> 4, h = bh & 15;
    const int row0 = blockIdx.x * 128;
    const int tid = threadIdx.x;
    const int lane = tid & 63, wid = tid >> 6;
    const size_t grow = (size_t)b * SEQ + row0;

    #pragma unroll
    for (int i = 0; i < 4; ++i) {
        int cl = i * 256 + tid;
        int r = cl >> 3, ci = cl & 7;
        int sci = ci ^ (r & 7);
        gload16(qr + (grow + r) * CH + h * HD + sci * 8, (ushort*)&As[cl * 8]);
    }
    #pragma unroll
    for (int i = 0; i < 2; ++i) {
        int cl = i * 256 + tid;
        int r = cl >> 3, ci = cl & 7;
        int sci = ci ^ (r & 7);
        gload16(kvT + (size_t)bh * 4096 + r * 64 + sci * 8, (ushort*)&Bs[cl * 8]);
    }
    asm volatile("s_waitcnt vmcnt(0)" ::: "memory");
    __syncthreads();

    f32x4 acc[2][4] = {};
    #pragma unroll
    for (int ks2 = 0; ks2 < 2; ++ks2) {
        s16x8 af[2], bfr[4];
        #pragma unroll
        for (int mi = 0; mi < 2; ++mi) {
            int r = wid * 32 + mi * 16 + (lane & 15);
            int ch = ((lane >> 4) + ks2 * 4) ^ (r & 7);
            af[mi] = *(const s16x8*)&As[r * 64 + ch * 8];
        }
        #pragma unroll
        for (int ni = 0; ni < 4; ++ni) {
            int e = ni * 16 + (lane & 15);
            int ch = ((lane >> 4) + ks2 * 4) ^ (e & 7);
            bfr[ni] = *(const s16x8*)&Bs[e * 64 + ch * 8];
        }
        #pragma unroll
        for (int mi = 0; mi < 2; ++mi)
            #pragma unroll
            for (int ni = 0; ni < 4; ++ni)
                acc[mi][ni] = __builtin_amdgcn_mfma_f32_16x16x32_bf16(af[mi], bfr[ni], acc[mi][ni], 0, 0, 0);
    }

    const float* zp = zin + (size_t)bh * SEQ + row0;
    #pragma unroll
    for (int mi = 0; mi < 2; ++mi) {
        int mb = wid * 32 + mi * 16 + ((lane >> 4) << 2);
        #pragma unroll
        for (int r = 0; r < 4; ++r) {
            float zv = zp[mb + r];
            #pragma unroll
            for (int ni = 0; ni < 4; ++ni) {
                int e = ni * 16 + (lane & 15);
                o[(grow + mb + r) * CH + h * HD + e] = f2bf(acc[mi][ni][r] * zv);
            }
        }
    }
}

// ---------------- residual + LayerNorm ----------------
__global__ __launch_bounds__(256) void ln_kernel(
    const ushort* __restrict__ o, const float* __restrict__ x,
    const float* __restrict__ gamma, const float* __restrict__ beta,
    float* __restrict__ out)
{
    const int row = blockIdx.x;
    const int tid = threadIdx.x;
    const size_t base = (size_t)row * CH + tid * 4;
    f32x4 xv = *(const f32x4*)(x + base);
    ushort4 ov = *(const ushort4*)(o + base);
    float v0 = bf2f(ov.x) + xv[0];
    float v1 = bf2f(ov.y) + xv[1];
    float v2 = bf2f(ov.z) + xv[2];
    float v3 = bf2f(ov.w) + xv[3];
    float s = v0 + v1 + v2 + v3;
    float q = v0 * v0 + v1 * v1 + v2 * v2 + v3 * v3;
    #pragma unroll
    for (int off = 1; off < 64; off <<= 1) {
        s += __shfl_xor(s, off);
        q += __shfl_xor(q, off);
    }
    __shared__ float red[8];
    int wv = tid >> 6;
    if ((tid & 63) == 0) { red[wv] = s; red[4 + wv] = q; }
    __syncthreads();
    s = red[0] + red[1] + red[2] + red[3];
    q = red[4] + red[5] + red[6] + red[7];
    float mean = s * (1.f / 1024.f);
    float var = q * (1.f / 1024.f) - mean * mean;
    float rstd = rsqrtf(var + 1e-12f);
    f32x4 gv = *(const f32x4*)(gamma + tid * 4);
    f32x4 bv = *(const f32x4*)(beta + tid * 4);
    f32x4 res;
    res[0] = (v0 - mean) * rstd * gv[0] + bv[0];
    res[1] = (v1 - mean) * rstd * gv[1] + bv[1];
    res[2] = (v2 - mean) * rstd * gv[2] + bv[2];
    res[3] = (v3 - mean) * rstd * gv[3] + bv[3];
    *(f32x4*)(out + base) = res;
}

extern "C" void kernel_launch(void* const* d_in, const int* in_sizes, int n_in,
                              void* d_out, int out_size, void* d_ws, size_t ws_size,
                              hipStream_t stream) {
    const float* x     = (const float*)d_in[0];
    const float* Wq    = (const float*)d_in[1];
    const float* bq    = (const float*)d_in[2];
    const float* Wk    = (const float*)d_in[3];
    const float* bk    = (const float*)d_in[4];
    const float* Wv    = (const float*)d_in[5];
    const float* bv    = (const float*)d_in[6];
    const float* gamma = (const float*)d_in[7];
    const float* beta  = (const float*)d_in[8];
    float* out = (float*)d_out;
    char* ws = (char*)d_ws;

    // workspace layout (bytes); total ~161 MiB
    ushort* xb   = (ushort*)(ws);                         // 32 MiB (reused as attn-out o)
    ushort* wb   = (ushort*)(ws + (size_t)32 * 1048576);  // 6 MiB
    float2* csT  = (float2*)(ws + (size_t)38 * 1048576);  // 8 MiB interleaved cos/sin
    ushort* qr   = (ushort*)(ws + (size_t)46  * 1048576); // 32 MiB
    ushort* kr   = (ushort*)(ws + (size_t)78  * 1048576); // 32 MiB
    ushort* vo   = (ushort*)(ws + (size_t)110 * 1048576); // 32 MiB
    float*  ksum = (float*) (ws + (size_t)142 * 1048576); // 32 KiB
    ushort* kvT  = (ushort*)(ws + (size_t)143 * 1048576); // 1 MiB
    float*  zbuf = (float*) (ws + (size_t)144 * 1048576); // 1 MiB
    float*  kvp  = (float*) (ws + (size_t)145 * 1048576); // 16 MiB
    ushort* o    = xb;  // reuse: xb dead after qkv_gemm

    hipMemsetAsync(ksum, 0, NB * CH * sizeof(float), stream);
    cvt_bf16_kernel<<<16384, 256, 0, stream>>>(x, xb, MROWS * CH / 4);
    cvt_bf16_kernel<<<1024, 256, 0, stream>>>(Wq, wb,                 CH * CH / 4);
    cvt_bf16_kernel<<<1024, 256, 0, stream>>>(Wk, wb + CH * CH,       CH * CH / 4);
    cvt_bf16_kernel<<<1024, 256, 0, stream>>>(Wv, wb + 2 * CH * CH,   CH * CH / 4);
    rope_table_kernel<<<SEQ * HALFC / 256, 256, 0, stream>>>(csT);
    qkv_gemm_kernel<<<dim3(8, 128, 3), 256, 0, stream>>>(xb, wb, bq, bk, bv, csT, qr, kr, vo, ksum);
    z_kernel<<<MROWS * NH / 256, 256, 0, stream>>>(qr, ksum, csT, zbuf);
    kv_partial_kernel<<<NB * NH * 8, 256, 0, stream>>>(kr, vo, kvp);
    kv_reduce_kernel<<<NB * NH * 4096 / 256, 256, 0, stream>>>(kvp, kvT);
    pv_kernel<<<dim3(16, 128), 256, 0, stream>>>(qr, kvT, zbuf, o);
    ln_kernel<<<MROWS, 256, 0, stream>>>(o, x, gamma, beta, out);
}

// Round 4
// 402.666 us; speedup vs baseline: 1.0881x; 1.0499x over previous
//
#include <hip/hip_runtime.h>
#include <cstdint>
#include <cstddef>

// Sizes (fixed by the problem)
#define NB 8
#define SEQ 2048
#define CH 1024
#define NH 16
#define HD 64
#define MROWS (NB*SEQ)   // 16384
#define HALFC 512

typedef __attribute__((ext_vector_type(4))) float f32x4;
typedef __attribute__((ext_vector_type(8))) short s16x8;

__device__ __forceinline__ ushort f2bf(float f) {
    union { float f; unsigned u; } v; v.f = f;
    unsigned r = (v.u + 0x7FFFu + ((v.u >> 16) & 1u)) >> 16;
    return (ushort)r;
}
__device__ __forceinline__ float bf2f(ushort u) {
    union { unsigned u; float f; } v; v.u = ((unsigned)u) << 16;
    return v.f;
}
__device__ __forceinline__ void gload16(const ushort* g, ushort* l) {
    __builtin_amdgcn_global_load_lds((const __attribute__((address_space(1))) unsigned*)g,
                                     (__attribute__((address_space(3))) unsigned*)l, 16, 0, 0);
}

// A&S 7.1.26 erf approximation, |err| <= 1.5e-7 (validated rounds 2-3)
__device__ __forceinline__ float fast_erf(float x) {
    float ax = fabsf(x);
    float d = __fmaf_rn(0.3275911f, ax, 1.f);
    float t; asm("v_rcp_f32 %0, %1" : "=v"(t) : "v"(d));
    float p = __fmaf_rn(1.061405429f, t, -1.453152027f);
    p = __fmaf_rn(p, t, 1.421413741f);
    p = __fmaf_rn(p, t, -0.284496736f);
    p = __fmaf_rn(p, t, 0.254829592f);
    p = p * t;
    float e = __expf(-ax * ax);
    float r = 1.f - p * e;
    return copysignf(r, x);
}

// ---------------- f32 -> bf16 convert ----------------
__global__ void cvt_bf16_kernel(const float* __restrict__ src, ushort* __restrict__ dst, int n4) {
    int i = blockIdx.x * 256 + threadIdx.x;
    if (i >= n4) return;
    f32x4 v = ((const f32x4*)src)[i];
    ushort4 o;
    o.x = f2bf(v[0]); o.y = f2bf(v[1]); o.z = f2bf(v[2]); o.w = f2bf(v[3]);
    ((ushort4*)dst)[i] = o;
}

// ---------------- rope cos/sin table (interleaved float2): [SEQ][HALFC] ----------------
__global__ void rope_table_kernel(float2* __restrict__ csT) {
    int idx = blockIdx.x * 256 + threadIdx.x;   // < SEQ*HALFC
    int n = idx >> 9;
    int i = idx & 511;
    // 10000^(-i/512) = 2^(-i*log2(10000)/512); exp2f avoids libm powf
    float freq = exp2f((float)i * (-13.287712379549449f / 512.f));
    float a = (float)n * freq;
    float s, c;
    sincosf(a, &s, &c);
    csT[idx] = make_float2(c, s);
}

// ---------------- fused QKV projection GEMM ----------------
// C[m, o] = sum_k x[m,k] * W[o,k]  (B^T layout, both k-contiguous)
// Proven r1/r3 sync structure (sync; stage; vmcnt(0); sync; compute) + T1 XCD swizzle.
// launch_bounds (256,4): VGPR cap 64 (compiler used 60 at cap 128) -> 4-5 blocks/CU
// for more implicit cross-block overlap of the barrier drain (m114 mechanism).
__global__ __launch_bounds__(256, 4) void qkv_gemm_kernel(
    const ushort* __restrict__ xb, const ushort* __restrict__ wb,
    const float* __restrict__ bq, const float* __restrict__ bk, const float* __restrict__ bv,
    const float2* __restrict__ csT,
    ushort* __restrict__ qr, ushort* __restrict__ kr, ushort* __restrict__ vo,
    float* __restrict__ ksum)
{
    __shared__ ushort As[128 * 64];
    __shared__ ushort Bs[128 * 64];
    const int z = blockIdx.z;
    const ushort* w = wb + (size_t)z * CH * CH;
    const float* bias = (z == 0) ? bq : (z == 1) ? bk : bv;
    ushort* dst = (z == 0) ? qr : (z == 1) ? kr : vo;
    // XCD swizzle: physical block p -> XCD p%8; XCD x owns logical [x*128,(x+1)*128)
    // (col-fastest) so its 8 B-panels (2 MiB) stay L2-resident.
    const int bid = blockIdx.x + 8 * blockIdx.y;       // physical 0..1023
    const int l = (bid & 7) * 128 + (bid >> 3);        // logical, bijective
    const int row0 = (l >> 3) * 128;
    const int col0 = (l & 7) * 128;
    const int tid = threadIdx.x;
    const int lane = tid & 63;
    const int wid = tid >> 6;
    const int wm = (wid >> 1) * 64;
    const int wn = (wid & 1) * 64;

    f32x4 acc[4][4] = {};

    for (int kt = 0; kt < CH; kt += 64) {
        __syncthreads();
        #pragma unroll
        for (int i = 0; i < 4; ++i) {
            int cl = i * 256 + tid;
            int r = cl >> 3, ci = cl & 7;
            int sci = ci ^ (r & 7);   // pre-swizzled source -> linear LDS (G4/m173)
            gload16(xb + (size_t)(row0 + r) * CH + kt + sci * 8, (ushort*)&As[cl * 8]);
            gload16(w  + (size_t)(col0 + r) * CH + kt + sci * 8, (ushort*)&Bs[cl * 8]);
        }
        asm volatile("s_waitcnt vmcnt(0)" ::: "memory");
        __syncthreads();
        #pragma unroll
        for (int ks = 0; ks < 2; ++ks) {
            s16x8 af[4], bfr[4];
            #pragma unroll
            for (int mi = 0; mi < 4; ++mi) {
                int r = wm + mi * 16 + (lane & 15);
                int ch = ((lane >> 4) + ks * 4) ^ (r & 7);
                af[mi] = *(const s16x8*)&As[r * 64 + ch * 8];
            }
            #pragma unroll
            for (int ni = 0; ni < 4; ++ni) {
                int r = wn + ni * 16 + (lane & 15);
                int ch = ((lane >> 4) + ks * 4) ^ (r & 7);
                bfr[ni] = *(const s16x8*)&Bs[r * 64 + ch * 8];
            }
            #pragma unroll
            for (int mi = 0; mi < 4; ++mi)
                #pragma unroll
                for (int ni = 0; ni < 4; ++ni)
                    acc[mi][ni] = __builtin_amdgcn_mfma_f32_16x16x32_bf16(af[mi], bfr[ni], acc[mi][ni], 0, 0, 0);
        }
    }

    // epilogue: bias -> (fast-gelu + 0.21, ksum, rope) or plain v
    const int bidx = row0 >> 11;  // batch index
    #pragma unroll
    for (int ni = 0; ni < 4; ++ni) {
        const int cg = col0 + wn + ni * 16 + (lane & 15);
        const float bsv = bias[cg];
        float cs = 0.f;
        #pragma unroll
        for (int mi = 0; mi < 4; ++mi) {
            const int mbase = row0 + wm + mi * 16 + ((lane >> 4) << 2);
            #pragma unroll
            for (int r = 0; r < 4; ++r) {
                float t = acc[mi][ni][r] + bsv;
                float val;
                if (z == 2) {
                    val = t;
                } else {
                    val = 0.5f * t * (1.f + fast_erf(t * 0.70710678f)) + 0.21f;
                }
                if (z == 1) cs += val;   // pre-rope k column sum
                if (z != 2) {
                    // interleaved-pair rope; partner col = cg^1 lives in lane^1 (col = lane&15)
                    float p = __shfl_xor(val, 1);
                    int n = (mbase + r) & (SEQ - 1);
                    float2 cv = csT[n * HALFC + (cg >> 1)];
                    val = (cg & 1) ? (p * cv.y + val * cv.x) : (val * cv.x - p * cv.y);
                }
                dst[(size_t)(mbase + r) * CH + cg] = f2bf(val);
            }
        }
        if (z == 1) {
            cs += __shfl_xor(cs, 16);
            cs += __shfl_xor(cs, 32);
            if (lane < 16) atomicAdd(&ksum[bidx * CH + cg], cs);
        }
    }
}

// ---------------- kv partials: kvp[blk][d][e] = sum_{n in chunk} k_r[n,d]*v[n,e] ----------------
__global__ __launch_bounds__(256, 2) void kv_partial_kernel(
    const ushort* __restrict__ kr, const ushort* __restrict__ vo, float* __restrict__ kvp)
{
    const int blk = blockIdx.x;
    const int chunk = blk & 7;
    const int bh = blk >> 3;
    const int b = bh >> 4, h = bh & 15;
    __shared__ float ks[64 * 68];
    __shared__ float vs[64 * 68];
    const int tid = threadIdx.x;
    const int d0 = (tid >> 4) * 4;
    const int e0 = (tid & 15) * 4;
    float acc[4][4] = {};
    const size_t base = ((size_t)b * SEQ + chunk * 256) * CH + h * HD;
    const int lrow = tid >> 2;
    const int lcol = (tid & 3) * 16;

    for (int it = 0; it < 4; ++it) {
        __syncthreads();
        const ushort* gk = kr + base + (size_t)(it * 64 + lrow) * CH + lcol;
        const ushort* gv = vo + base + (size_t)(it * 64 + lrow) * CH + lcol;
        s16x8 ka = *(const s16x8*)gk, kb2 = *(const s16x8*)(gk + 8);
        s16x8 va = *(const s16x8*)gv, vb2 = *(const s16x8*)(gv + 8);
        #pragma unroll
        for (int seg = 0; seg < 2; ++seg) {
            s16x8 kk = seg ? kb2 : ka;
            s16x8 vv = seg ? vb2 : va;
            #pragma unroll
            for (int q = 0; q < 2; ++q) {
                f32x4 tk, tv;
                #pragma unroll
                for (int e = 0; e < 4; ++e) {
                    tk[e] = bf2f((ushort)kk[q * 4 + e]);
                    tv[e] = bf2f((ushort)vv[q * 4 + e]);
                }
                *(f32x4*)&ks[lrow * 68 + lcol + seg * 8 + q * 4] = tk;
                *(f32x4*)&vs[lrow * 68 + lcol + seg * 8 + q * 4] = tv;
            }
        }
        __syncthreads();
        for (int n = 0; n < 64; ++n) {
            f32x4 kq = *(const f32x4*)&ks[n * 68 + d0];
            f32x4 vq = *(const f32x4*)&vs[n * 68 + e0];
            #pragma unroll
            for (int di = 0; di < 4; ++di)
                #pragma unroll
                for (int ej = 0; ej < 4; ++ej)
                    acc[di][ej] += kq[di] * vq[ej];
        }
    }
    float* op = kvp + (size_t)blk * 4096;
    #pragma unroll
    for (int di = 0; di < 4; ++di) {
        f32x4 t;
        t[0] = acc[di][0]; t[1] = acc[di][1]; t[2] = acc[di][2]; t[3] = acc[di][3];
        *(f32x4*)&op[(d0 + di) * 64 + e0] = t;
    }
}

// ---------------- kv reduce: kvT[bh][e][d] (bf16) = (1/2048) * sum_c kvp ----------------
__global__ void kv_reduce_kernel(const float* __restrict__ kvp, ushort* __restrict__ kvT) {
    int idx = blockIdx.x * 256 + threadIdx.x;   // < 128*4096
    int bh = idx >> 12;
    int de = idx & 4095;
    int e = de >> 6, d = de & 63;
    float s = 0.f;
    #pragma unroll
    for (int c = 0; c < 8; ++c)
        s += kvp[((size_t)bh * 8 + c) * 4096 + d * 64 + e];
    kvT[idx] = f2bf(s * (1.f / 2048.f));
}

// ---------------- PV + fused z: o[n, h*64+e] = z_n * sum_d q_r[n,h*64+d] * kvT[e,d] ----------------
// z fused here: As already holds the q_r head slice; z_n = 1/(q_r . R_n(kmean) + 1e-6)
// since rope is a pairwise rotation: q.km == q_r.R_n(km).
__global__ __launch_bounds__(256, 2) void pv_kernel(
    const ushort* __restrict__ qr, const ushort* __restrict__ kvT,
    const float* __restrict__ ksum, const float2* __restrict__ csT,
    ushort* __restrict__ o)
{
    __shared__ ushort As[128 * 64];
    __shared__ ushort Bs[64 * 64];
    __shared__ float zrow[128];
    const int bh = blockIdx.y;
    const int b = bh >> 4, h = bh & 15;
    const int row0 = blockIdx.x * 128;
    const int tid = threadIdx.x;
    const int lane = tid & 63, wid = tid >> 6;
    const size_t grow = (size_t)b * SEQ + row0;

    #pragma unroll
    for (int i = 0; i < 4; ++i) {
        int cl = i * 256 + tid;
        int r = cl >> 3, ci = cl & 7;
        int sci = ci ^ (r & 7);
        gload16(qr + (grow + r) * CH + h * HD + sci * 8, (ushort*)&As[cl * 8]);
    }
    #pragma unroll
    for (int i = 0; i < 2; ++i) {
        int cl = i * 256 + tid;
        int r = cl >> 3, ci = cl & 7;
        int sci = ci ^ (r & 7);
        gload16(kvT + (size_t)bh * 4096 + r * 64 + sci * 8, (ushort*)&Bs[cl * 8]);
    }
    asm volatile("s_waitcnt vmcnt(0)" ::: "memory");
    __syncthreads();

    // z: 2 threads per row; thread t -> row r=t>>1, half hh=t&1 (pairs hh*16..hh*16+15)
    {
        const int r = tid >> 1, hh = tid & 1;
        const int n = row0 + r;
        const float* kmp = ksum + b * CH + h * HD + hh * 32;
        const float2* cp = csT + (size_t)n * HALFC + h * 32 + hh * 16;
        float part = 0.f;
        #pragma unroll
        for (int cc = 0; cc < 4; ++cc) {
            int chunk = hh * 4 + cc;                       // global 8-elem chunk index
            s16x8 qv = *(const s16x8*)&As[r * 64 + (chunk ^ (r & 7)) * 8];
            #pragma unroll
            for (int j = 0; j < 4; ++j) {                  // 4 pairs per chunk
                float q0 = bf2f((ushort)qv[2 * j]);
                float q1 = bf2f((ushort)qv[2 * j + 1]);
                float km0 = kmp[cc * 8 + 2 * j];
                float km1 = kmp[cc * 8 + 2 * j + 1];
                float2 cv = cp[cc * 4 + j];
                part += q0 * (km0 * cv.x - km1 * cv.y) + q1 * (km0 * cv.y + km1 * cv.x);
            }
        }
        part += __shfl_xor(part, 1);                       // lanes 2r,2r+1 adjacent
        if (hh == 0) zrow[r] = 1.f / (part * (1.f / 2048.f) + 1e-6f);
    }

    f32x4 acc[2][4] = {};
    #pragma unroll
    for (int ks2 = 0; ks2 < 2; ++ks2) {
        s16x8 af[2], bfr[4];
        #pragma unroll
        for (int mi = 0; mi < 2; ++mi) {
            int r = wid * 32 + mi * 16 + (lane & 15);
            int ch = ((lane >> 4) + ks2 * 4) ^ (r & 7);
            af[mi] = *(const s16x8*)&As[r * 64 + ch * 8];
        }
        #pragma unroll
        for (int ni = 0; ni < 4; ++ni) {
            int e = ni * 16 + (lane & 15);
            int ch = ((lane >> 4) + ks2 * 4) ^ (e & 7);
            bfr[ni] = *(const s16x8*)&Bs[e * 64 + ch * 8];
        }
        #pragma unroll
        for (int mi = 0; mi < 2; ++mi)
            #pragma unroll
            for (int ni = 0; ni < 4; ++ni)
                acc[mi][ni] = __builtin_amdgcn_mfma_f32_16x16x32_bf16(af[mi], bfr[ni], acc[mi][ni], 0, 0, 0);
    }

    __syncthreads();   // zrow visible to all waves

    #pragma unroll
    for (int mi = 0; mi < 2; ++mi) {
        int mb = wid * 32 + mi * 16 + ((lane >> 4) << 2);
        #pragma unroll
        for (int r = 0; r < 4; ++r) {
            float zv = zrow[mb + r];
            #pragma unroll
            for (int ni = 0; ni < 4; ++ni) {
                int e = ni * 16 + (lane & 15);
                o[(grow + mb + r) * CH + h * HD + e] = f2bf(acc[mi][ni][r] * zv);
            }
        }
    }
}

// ---------------- residual + LayerNorm ----------------
__global__ __launch_bounds__(256) void ln_kernel(
    const ushort* __restrict__ o, const float* __restrict__ x,
    const float* __restrict__ gamma, const float* __restrict__ beta,
    float* __restrict__ out)
{
    const int row = blockIdx.x;
    const int tid = threadIdx.x;
    const size_t base = (size_t)row * CH + tid * 4;
    f32x4 xv = *(const f32x4*)(x + base);
    ushort4 ov = *(const ushort4*)(o + base);
    float v0 = bf2f(ov.x) + xv[0];
    float v1 = bf2f(ov.y) + xv[1];
    float v2 = bf2f(ov.z) + xv[2];
    float v3 = bf2f(ov.w) + xv[3];
    float s = v0 + v1 + v2 + v3;
    float q = v0 * v0 + v1 * v1 + v2 * v2 + v3 * v3;
    #pragma unroll
    for (int off = 1; off < 64; off <<= 1) {
        s += __shfl_xor(s, off);
        q += __shfl_xor(q, off);
    }
    __shared__ float red[8];
    int wv = tid >> 6;
    if ((tid & 63) == 0) { red[wv] = s; red[4 + wv] = q; }
    __syncthreads();
    s = red[0] + red[1] + red[2] + red[3];
    q = red[4] + red[5] + red[6] + red[7];
    float mean = s * (1.f / 1024.f);
    float var = q * (1.f / 1024.f) - mean * mean;
    float rstd = rsqrtf(var + 1e-12f);
    f32x4 gv = *(const f32x4*)(gamma + tid * 4);
    f32x4 bv = *(const f32x4*)(beta + tid * 4);
    f32x4 res;
    res[0] = (v0 - mean) * rstd * gv[0] + bv[0];
    res[1] = (v1 - mean) * rstd * gv[1] + bv[1];
    res[2] = (v2 - mean) * rstd * gv[2] + bv[2];
    res[3] = (v3 - mean) * rstd * gv[3] + bv[3];
    *(f32x4*)(out + base) = res;
}

extern "C" void kernel_launch(void* const* d_in, const int* in_sizes, int n_in,
                              void* d_out, int out_size, void* d_ws, size_t ws_size,
                              hipStream_t stream) {
    const float* x     = (const float*)d_in[0];
    const float* Wq    = (const float*)d_in[1];
    const float* bq    = (const float*)d_in[2];
    const float* Wk    = (const float*)d_in[3];
    const float* bk    = (const float*)d_in[4];
    const float* Wv    = (const float*)d_in[5];
    const float* bv    = (const float*)d_in[6];
    const float* gamma = (const float*)d_in[7];
    const float* beta  = (const float*)d_in[8];
    float* out = (float*)d_out;
    char* ws = (char*)d_ws;

    // workspace layout (bytes); total ~161 MiB
    ushort* xb   = (ushort*)(ws);                         // 32 MiB (reused as attn-out o)
    ushort* wb   = (ushort*)(ws + (size_t)32 * 1048576);  // 6 MiB
    float2* csT  = (float2*)(ws + (size_t)38 * 1048576);  // 8 MiB interleaved cos/sin
    ushort* qr   = (ushort*)(ws + (size_t)46  * 1048576); // 32 MiB
    ushort* kr   = (ushort*)(ws + (size_t)78  * 1048576); // 32 MiB
    ushort* vo   = (ushort*)(ws + (size_t)110 * 1048576); // 32 MiB
    float*  ksum = (float*) (ws + (size_t)142 * 1048576); // 32 KiB
    ushort* kvT  = (ushort*)(ws + (size_t)143 * 1048576); // 1 MiB
    float*  kvp  = (float*) (ws + (size_t)145 * 1048576); // 16 MiB
    ushort* o    = xb;  // reuse: xb dead after qkv_gemm

    hipMemsetAsync(ksum, 0, NB * CH * sizeof(float), stream);
    cvt_bf16_kernel<<<16384, 256, 0, stream>>>(x, xb, MROWS * CH / 4);
    cvt_bf16_kernel<<<1024, 256, 0, stream>>>(Wq, wb,                 CH * CH / 4);
    cvt_bf16_kernel<<<1024, 256, 0, stream>>>(Wk, wb + CH * CH,       CH * CH / 4);
    cvt_bf16_kernel<<<1024, 256, 0, stream>>>(Wv, wb + 2 * CH * CH,   CH * CH / 4);
    rope_table_kernel<<<SEQ * HALFC / 256, 256, 0, stream>>>(csT);
    qkv_gemm_kernel<<<dim3(8, 128, 3), 256, 0, stream>>>(xb, wb, bq, bk, bv, csT, qr, kr, vo, ksum);
    kv_partial_kernel<<<NB * NH * 8, 256, 0, stream>>>(kr, vo, kvp);
    kv_reduce_kernel<<<NB * NH * 4096 / 256, 256, 0, stream>>>(kvp, kvT);
    pv_kernel<<<dim3(16, 128), 256, 0, stream>>>(qr, kvT, ksum, csT, o);
    ln_kernel<<<MROWS, 256, 0, stream>>>(o, x, gamma, beta, out);
}